// Round 1
// baseline (6198.325 us; speedup 1.0000x reference)
//
#include <hip/hip_runtime.h>
#include <math.h>

#define S 512
#define B 64
#define I 1024
#define HD 1024
#define G4 (4*HD)

typedef _Float16 half8 __attribute__((ext_vector_type(8)));
typedef float floatx4 __attribute__((ext_vector_type(4)));
typedef float f32x4 __attribute__((ext_vector_type(4)));

// ---------- prep kernels ----------

__global__ void cast_f32_to_f16(const float* __restrict__ src,
                                _Float16* __restrict__ dst, long n8) {
    long i = (long)blockIdx.x * blockDim.x + threadIdx.x;
    if (i >= n8) return;
    const f32x4* s = (const f32x4*)src + i * 2;
    f32x4 a = s[0], b = s[1];
    half8 h;
    h[0] = (_Float16)a[0]; h[1] = (_Float16)a[1];
    h[2] = (_Float16)a[2]; h[3] = (_Float16)a[3];
    h[4] = (_Float16)b[0]; h[5] = (_Float16)b[1];
    h[6] = (_Float16)b[2]; h[7] = (_Float16)b[3];
    *((half8*)dst + i) = h;
}

__global__ void init_state(const float* __restrict__ h0, const float* __restrict__ c0,
                           const float* __restrict__ bi, const float* __restrict__ bh,
                           _Float16* __restrict__ hb0, float* __restrict__ cbuf,
                           float* __restrict__ bsum) {
    int i = blockIdx.x * blockDim.x + threadIdx.x;
    if (i < B * HD) {
        hb0[i] = (_Float16)h0[i];
        cbuf[i] = c0[i];
    }
    if (i < G4) bsum[i] = bi[i] + bh[i];
}

// ---------- recurrent step ----------
// Grid: 256 blocks x 256 threads (4 waves).
// Block m owns hidden units j in [4m, 4m+4): global W rows {g*HD + j} for gate g=0..3.
// Local row r_loc maps to (gate = r_loc&3, j = 4m + (r_loc>>2)).
// MFMA 16x16x32 f16:  A[16][32] lane l -> row=l&15, k=(l>>4)*8+j
//                     B[32][16] lane l -> col=l&15, k=(l>>4)*8+j
//                     D lane l -> col=l&15, row=(l>>4)*4+r
// => lane l of wave w holds pre[gate r][batch 16w+(l&15)] for hidden unit 4m+(l>>4).

__global__ __launch_bounds__(256) void lstm_step(
    const _Float16* __restrict__ xb,   // (S,B,I) f16
    const _Float16* __restrict__ Wib,  // (4H,I)  f16
    const _Float16* __restrict__ Whb,  // (4H,H)  f16
    const float*    __restrict__ bsum, // (4H) bi+bh
    const _Float16* __restrict__ hin,  // (B,H) f16
    _Float16*       __restrict__ hout, // (B,H) f16
    float*          __restrict__ cbuf, // (B,H) f32
    float*          __restrict__ out,  // (S,B,H) f32 [+ h_f + c_f]
    int t)
{
    __shared__ _Float16 Wl[2][16][1032];   // +8 f16 pad: 2-way bank alias (free)

    const int m = blockIdx.x;
    const int tid = threadIdx.x;
    const int l = tid & 63, w = tid >> 6;

    // Stage 16 rows of Wi and Wh into LDS (16B chunks, coalesced per row).
    for (int idx = tid; idx < 16 * 128; idx += 256) {
        int r = idx >> 7;
        int ch = (idx & 127) * 8;
        int grow = (r & 3) * HD + (m * 4 + (r >> 2));
        *(half8*)&Wl[0][r][ch] = *(const half8*)&Wib[(size_t)grow * I + ch];
        *(half8*)&Wl[1][r][ch] = *(const half8*)&Whb[(size_t)grow * HD + ch];
    }
    __syncthreads();

    const int bq = 16 * w + (l & 15);      // batch index this lane produces
    const int kq = (l >> 4) * 8;           // k-offset within 32-wide K step
    const _Float16* xrow = xb + ((size_t)t * B + bq) * I + kq;
    const _Float16* hrow = hin + (size_t)bq * HD + kq;
    const _Float16* wxp = &Wl[0][l & 15][kq];
    const _Float16* whp = &Wl[1][l & 15][kq];

    floatx4 acc = {0.f, 0.f, 0.f, 0.f};
    #pragma unroll 4
    for (int k = 0; k < I; k += 32) {
        half8 af = *(const half8*)(wxp + k);
        half8 bf = *(const half8*)(xrow + k);
        acc = __builtin_amdgcn_mfma_f32_16x16x32_f16(af, bf, acc, 0, 0, 0);
    }
    #pragma unroll 4
    for (int k = 0; k < HD; k += 32) {
        half8 af = *(const half8*)(whp + k);
        half8 bf = *(const half8*)(hrow + k);
        acc = __builtin_amdgcn_mfma_f32_16x16x32_f16(af, bf, acc, 0, 0, 0);
    }

    const int j = m * 4 + (l >> 4);        // hidden unit
    float pi = acc[0] + bsum[j];
    float pf = acc[1] + bsum[HD + j];
    float po = acc[2] + bsum[2 * HD + j];
    float pg = acc[3] + bsum[3 * HD + j];

    float ig = 1.f / (1.f + expf(-pi));
    float fg = 1.f / (1.f + expf(-pf));
    float og = 1.f / (1.f + expf(-po));
    float gg = tanhf(pg);

    size_t cix = (size_t)bq * HD + j;
    float ct = cbuf[cix] * fg + ig * gg;
    float ht = og * tanhf(ct);
    cbuf[cix] = ct;
    hout[cix] = (_Float16)ht;
    out[((size_t)t * B + bq) * HD + j] = ht;
    if (t == S - 1) {
        out[(size_t)S * B * HD + cix] = ht;                       // h_f
        out[(size_t)S * B * HD + (size_t)B * HD + cix] = ct;      // c_f
    }
}

// ---------- launch ----------

extern "C" void kernel_launch(void* const* d_in, const int* in_sizes, int n_in,
                              void* d_out, int out_size, void* d_ws, size_t ws_size,
                              hipStream_t stream) {
    const float* x  = (const float*)d_in[0];
    const float* h0 = (const float*)d_in[1];
    const float* c0 = (const float*)d_in[2];
    const float* Wi = (const float*)d_in[3];
    const float* bi = (const float*)d_in[4];
    const float* Wh = (const float*)d_in[5];
    const float* bh = (const float*)d_in[6];
    float* out = (float*)d_out;

    char* p = (char*)d_ws;
    _Float16* xb  = (_Float16*)p; p += (size_t)S * B * I * 2;
    _Float16* Wib = (_Float16*)p; p += (size_t)G4 * I * 2;
    _Float16* Whb = (_Float16*)p; p += (size_t)G4 * HD * 2;
    _Float16* hb0 = (_Float16*)p; p += (size_t)B * HD * 2;
    _Float16* hb1 = (_Float16*)p; p += (size_t)B * HD * 2;
    float* cbuf   = (float*)p;    p += (size_t)B * HD * 4;
    float* bsum   = (float*)p;    p += (size_t)G4 * 4;

    long nx8 = (long)S * B * I / 8;
    cast_f32_to_f16<<<(int)((nx8 + 255) / 256), 256, 0, stream>>>(x, xb, nx8);
    long nw8 = (long)G4 * I / 8;
    cast_f32_to_f16<<<(int)((nw8 + 255) / 256), 256, 0, stream>>>(Wi, Wib, nw8);
    cast_f32_to_f16<<<(int)((nw8 + 255) / 256), 256, 0, stream>>>(Wh, Whb, nw8);
    init_state<<<(B * HD + 255) / 256, 256, 0, stream>>>(h0, c0, bi, bh, hb0, cbuf, bsum);

    for (int t = 0; t < S; ++t) {
        _Float16* hin  = (t & 1) ? hb1 : hb0;
        _Float16* hout = (t & 1) ? hb0 : hb1;
        lstm_step<<<256, 256, 0, stream>>>(xb, Wib, Whb, bsum, hin, hout, cbuf, out, t);
    }
}